// Round 10
// baseline (57.958 us; speedup 1.0000x reference)
//
#include <hip/hip_runtime.h>

#define TPB 256
#define WPT 4                 // 16-row tiles per wave-chunk -> 64 rows/chunk
#define ROW_DW 20             // per-row LDS: xa[4] + h[16] dwords
#define LDS_ROW_F32 (64 * ROW_DW)        // 1280
#define LDS_MU_F32 192                    // 64 rows x 3
#define LDS_WAVE_F32 (LDS_ROW_F32 + 2 * LDS_MU_F32)   // 1664 f32 = 6656 B
#define NBLOCKS 1024          // 4096 waves == 16 waves/CU, exactly resident

typedef _Float16 half8 __attribute__((ext_vector_type(8)));
typedef __fp16  fp16x2 __attribute__((ext_vector_type(2)));
typedef float f32x4 __attribute__((ext_vector_type(4)));

__device__ __forceinline__ float fast_sigmoid(float x) {
    return __builtin_amdgcn_rcpf(1.0f + __expf(-x));
}
__device__ __forceinline__ float fast_tanh(float x) {
    return 2.0f * __builtin_amdgcn_rcpf(1.0f + __expf(-2.0f * x)) - 1.0f;
}
__device__ __forceinline__ half8 pack8(float4 lo, float4 hi) {
    union { fp16x2 p[4]; half8 h; } u;
    u.p[0] = __builtin_amdgcn_cvt_pkrtz(lo.x, lo.y);
    u.p[1] = __builtin_amdgcn_cvt_pkrtz(lo.z, lo.w);
    u.p[2] = __builtin_amdgcn_cvt_pkrtz(hi.x, hi.y);
    u.p[3] = __builtin_amdgcn_cvt_pkrtz(hi.z, hi.w);
    return u.h;
}

// ---- ws layout ----
// halfs: 6 tiles x 512 halfs (r, z, n_i, n_h, hp-identity, A2) = 6144 B
// byte 6144: float4 bias[16] per gate col {b_r, b_z, b_ni, b_nh} = 256 B
// A k-map: k0-3 = x(z0,z1,z2,act), k4-19 = h0..15, k20-31 = 0
// A2 rows m: 0-2 = W_mu, 3-5 = W_lv; k20 = bias slot (B2[20][n] = 1.0)

__global__ __launch_bounds__(64) void prep_kernel(
    const float* __restrict__ W_ih, const float* __restrict__ W_hh,
    const float* __restrict__ b_ih, const float* __restrict__ b_hh,
    const float* __restrict__ W_mu, const float* __restrict__ b_mu,
    const float* __restrict__ W_lv, const float* __restrict__ b_lv,
    void* __restrict__ wsv)
{
    _Float16* wsB = (_Float16*)wsv;
    const int l = threadIdx.x;
    const int col = l & 15, kg = l >> 4;

    #pragma unroll
    for (int t = 0; t < 4; ++t) {
        const int gate = (t == 0) ? col : (t == 1) ? (16 + col) : (32 + col);
        #pragma unroll
        for (int i = 0; i < 8; ++i) {
            const int k = kg * 8 + i;
            float v = 0.f;
            if (t <= 1) {
                if (k < 4)       v = W_ih[gate * 4 + k];
                else if (k < 20) v = W_hh[gate * 16 + (k - 4)];
            } else if (t == 2) {
                if (k < 4)       v = W_ih[gate * 4 + k];
            } else {
                if (k >= 4 && k < 20) v = W_hh[gate * 16 + (k - 4)];
            }
            wsB[t * 512 + l * 8 + i] = (_Float16)v;
        }
    }
    // tile 4: hp identity  B[k][n] = (k == n+4)
    #pragma unroll
    for (int i = 0; i < 8; ++i) {
        const int k = kg * 8 + i;
        wsB[4 * 512 + l * 8 + i] = (_Float16)((k == col + 4) ? 1.f : 0.f);
    }
    // tile 5: A2  lane holds A2[m = col][k = kg*8+i]
    #pragma unroll
    for (int i = 0; i < 8; ++i) {
        const int k = kg * 8 + i;
        const int m = col;
        float v = 0.f;
        if (m < 3) {
            if (k < 16)       v = W_mu[m * 16 + k];
            else if (k == 20) v = b_mu[m];
        } else if (m < 6) {
            if (k < 16)       v = W_lv[(m - 3) * 16 + k];
            else if (k == 20) v = b_lv[m - 3];
        }
        wsB[5 * 512 + l * 8 + i] = (_Float16)v;
    }
    if (l < 16) {
        float4* b4 = (float4*)((char*)wsv + 6144);
        b4[l] = make_float4(b_ih[l] + b_hh[l],
                            b_ih[16 + l] + b_hh[16 + l],
                            b_ih[32 + l],
                            b_hh[32 + l]);
    }
}

__global__ __launch_bounds__(TPB) void rssm_kernel(
    const float* __restrict__ prev_z,   // [B,3]
    const float* __restrict__ action,   // [B,1]
    const float* __restrict__ prev_h,   // [B,16]
    const void*  __restrict__ wsv,
    float* __restrict__ out_mu,         // [B,3]
    float* __restrict__ out_lv,         // [B,3]
    float* __restrict__ out_h,          // [B,16]
    int B)
{
    __shared__ float lds[4][LDS_WAVE_F32];
    const int tid = threadIdx.x;
    const int wid = tid >> 6, lane = tid & 63;
    const int col = lane & 15, kg = lane >> 4;

    float* W  = lds[wid];
    float* MU = W + LDS_ROW_F32;
    float* LV = MU + LDS_MU_F32;

    // ---- wave-invariant fragments (once per wave, amortized over all chunks) ----
    const half8* Bp = (const half8*)wsv;
    const half8 bR  = Bp[lane];
    const half8 bZ  = Bp[64 + lane];
    const half8 bNi = Bp[128 + lane];
    const half8 bNh = Bp[192 + lane];
    const half8 bHp = Bp[256 + lane];
    const half8 a2  = Bp[320 + lane];
    const float4 bias = ((const float4*)((const char*)wsv + 6144))[col];

    const int stride = NBLOCKS * 4;          // chunks per sweep (4096)
    int chunk = blockIdx.x * 4 + wid;
    if (chunk * 64 >= B) return;

    const float4* hg = (const float4*)prev_h;

    // ---- prefetch chunk 0 into registers ----
    float4 hreg[4], xar;
    {
        const int cb4 = chunk * 256;         // cbase*4
        #pragma unroll
        for (int i = 0; i < 4; ++i)
            hreg[i] = hg[min(cb4 + i * 64 + lane, B * 4 - 1)];
        const int zr = min(chunk * 64 + lane, B - 1);
        xar = make_float4(prev_z[zr * 3 + 0], prev_z[zr * 3 + 1],
                          prev_z[zr * 3 + 2], action[zr]);
    }

    while (true) {
        const int cbase = chunk * 64;

        // ---- write staged regs to this wave's LDS slice ----
        #pragma unroll
        for (int i = 0; i < 4; ++i) {
            const int fi = i * 64 + lane;
            const int r = fi >> 2, w = fi & 3;
            *(float4*)&W[r * ROW_DW + 4 + w * 4] = hreg[i];
        }
        *(float4*)&W[lane * ROW_DW] = xar;

        // ---- issue next chunk's global loads (latency hides under compute) ----
        const int nchunk = chunk + stride;
        const bool have_next = (nchunk * 64 < B);
        if (have_next) {
            const int cb4 = nchunk * 256;
            #pragma unroll
            for (int i = 0; i < 4; ++i)
                hreg[i] = hg[min(cb4 + i * 64 + lane, B * 4 - 1)];
            const int zr = min(nchunk * 64 + lane, B - 1);
            xar = make_float4(prev_z[zr * 3 + 0], prev_z[zr * 3 + 1],
                              prev_z[zr * 3 + 2], action[zr]);
        }

        // ---- compute this chunk from LDS ----
        #pragma unroll
        for (int t = 0; t < WPT; ++t) {
            // A fragment (uniform LDS reads; k>=20 lanes hold zeros)
            const float* ap = &W[(t * 16 + col) * ROW_DW + kg * 8];
            const float4 z4 = make_float4(0.f, 0.f, 0.f, 0.f);
            const float4 p0 = (kg < 3) ? *(const float4*)ap : z4;
            const float4 p1 = (kg < 2) ? *(const float4*)(ap + 4) : z4;
            const half8 a = pack8(p0, p1);

            f32x4 accR  = {bias.x, bias.x, bias.x, bias.x};
            f32x4 accZ  = {bias.y, bias.y, bias.y, bias.y};
            f32x4 accNi = {bias.z, bias.z, bias.z, bias.z};
            f32x4 accNh = {bias.w, bias.w, bias.w, bias.w};
            f32x4 accHp = {0.f, 0.f, 0.f, 0.f};
            accR  = __builtin_amdgcn_mfma_f32_16x16x32_f16(a, bR,  accR,  0, 0, 0);
            accZ  = __builtin_amdgcn_mfma_f32_16x16x32_f16(a, bZ,  accZ,  0, 0, 0);
            accNi = __builtin_amdgcn_mfma_f32_16x16x32_f16(a, bNi, accNi, 0, 0, 0);
            accNh = __builtin_amdgcn_mfma_f32_16x16x32_f16(a, bNh, accNh, 0, 0, 0);
            accHp = __builtin_amdgcn_mfma_f32_16x16x32_f16(a, bHp, accHp, 0, 0, 0);

            // gates; write hn back into the LDS h-slot
            #pragma unroll
            for (int q = 0; q < 4; ++q) {
                const float r  = fast_sigmoid(accR[q]);
                const float z  = fast_sigmoid(accZ[q]);
                const float n  = fast_tanh(fmaf(r, accNh[q], accNi[q]));
                const float hv = fmaf(z, accHp[q] - n, n);   // (1-z)*n + z*h
                W[(t * 16 + kg * 4 + q) * ROW_DW + 4 + col] = hv;
            }

            // head MFMA: B2[k][n=col] = hn[col][k]
            half8 b2;
            if (kg < 2) {
                const float* hr = &W[(t * 16 + col) * ROW_DW + 4 + kg * 8];
                b2 = pack8(*(const float4*)hr, *(const float4*)(hr + 4));
            } else {
                #pragma unroll
                for (int i = 0; i < 8; ++i) b2[i] = (_Float16)0.f;
                if (kg == 2) b2[4] = (_Float16)1.0f;         // k=20 bias slot
            }
            f32x4 acc2 = {0.f, 0.f, 0.f, 0.f};
            acc2 = __builtin_amdgcn_mfma_f32_16x16x32_f16(a2, b2, acc2, 0, 0, 0);

            // mu/lv into LDS (clamped), packed [row][3] per stream
            const int mr = (t * 16 + col) * 3;
            if (kg == 0) {
                MU[mr + 0] = acc2[0];
                MU[mr + 1] = acc2[1];
                MU[mr + 2] = acc2[2];
                LV[mr + 0] = fminf(fmaxf(acc2[3], -5.0f), 5.0f);
            } else if (kg == 1) {
                LV[mr + 1] = fminf(fmaxf(acc2[0], -5.0f), 5.0f);
                LV[mr + 2] = fminf(fmaxf(acc2[1], -5.0f), 5.0f);
            }

            // cooperative out_h store for this tile (1 KB contiguous)
            {
                const int r = lane >> 2, w = lane & 3;
                const float4 hv4 = *(const float4*)&W[(t * 16 + r) * ROW_DW + 4 + w * 4];
                const int orow = cbase + t * 16 + r;
                if (orow < B)
                    *(float4*)&out_h[(size_t)orow * 16 + w * 4] = hv4;
            }
        }

        // cooperative mu / lv stores (768 B contiguous each)
        if (lane < 48) {
            const int gi = cbase * 3 + lane * 4;
            if (gi + 3 < B * 3) {
                *(float4*)&out_mu[gi] = *(const float4*)&MU[lane * 4];
                *(float4*)&out_lv[gi] = *(const float4*)&LV[lane * 4];
            }
        }

        if (!have_next) break;
        chunk = nchunk;
    }
}

extern "C" void kernel_launch(void* const* d_in, const int* in_sizes, int n_in,
                              void* d_out, int out_size, void* d_ws, size_t ws_size,
                              hipStream_t stream) {
    const float* prev_z = (const float*)d_in[0];
    const float* action = (const float*)d_in[1];
    const float* prev_h = (const float*)d_in[2];
    const float* W_ih   = (const float*)d_in[3];
    const float* W_hh   = (const float*)d_in[4];
    const float* b_ih   = (const float*)d_in[5];
    const float* b_hh   = (const float*)d_in[6];
    const float* W_mu   = (const float*)d_in[7];
    const float* b_mu   = (const float*)d_in[8];
    const float* W_lv   = (const float*)d_in[9];
    const float* b_lv   = (const float*)d_in[10];

    const int B = in_sizes[0] / 3;
    float* out    = (float*)d_out;
    float* out_mu = out;
    float* out_lv = out + (size_t)3 * B;
    float* out_h  = out + (size_t)6 * B;

    prep_kernel<<<1, 64, 0, stream>>>(W_ih, W_hh, b_ih, b_hh,
                                      W_mu, b_mu, W_lv, b_lv, d_ws);

    const int total_chunks = (B + 63) / 64;
    int blocks = NBLOCKS;
    if (total_chunks < NBLOCKS * 4)
        blocks = (total_chunks + 3) / 4;
    rssm_kernel<<<blocks, TPB, 0, stream>>>(prev_z, action, prev_h, d_ws,
                                            out_mu, out_lv, out_h, B);
}

// Round 11
// 41.524 us; speedup vs baseline: 1.3958x; 1.3958x over previous
//
#include <hip/hip_runtime.h>

#define TPB 256
#define WPT 4                 // 16-row tiles per wave -> 64 rows/wave, 256/block
#define ROW_DW 20             // per-row LDS: xa[4] + h[16] dwords
#define LDS_ROW_F32 (64 * ROW_DW)        // 1280
#define LDS_MU_F32 192                    // 64 rows x 3
#define LDS_WAVE_F32 (LDS_ROW_F32 + 2 * LDS_MU_F32)   // 1664 f32 = 6656 B
#define LOG2E 1.44269504088896340736f

typedef _Float16 half8 __attribute__((ext_vector_type(8)));
typedef __fp16  fp16x2 __attribute__((ext_vector_type(2)));
typedef float f32x4 __attribute__((ext_vector_type(4)));

__device__ __forceinline__ half8 pack8(float4 lo, float4 hi) {
    union { fp16x2 p[4]; half8 h; } u;
    u.p[0] = __builtin_amdgcn_cvt_pkrtz(lo.x, lo.y);
    u.p[1] = __builtin_amdgcn_cvt_pkrtz(lo.z, lo.w);
    u.p[2] = __builtin_amdgcn_cvt_pkrtz(hi.x, hi.y);
    u.p[3] = __builtin_amdgcn_cvt_pkrtz(hi.z, hi.w);
    return u.h;
}

// ---- ws layout ----
// halfs: 6 tiles x 512 halfs (r, z, n_i, n_h, hp-identity, A2) = 6144 B
// byte 6144: float4 bias[16] per gate col {b_r, b_z, b_ni, b_nh} = 256 B
// r,z tiles+biases pre-scaled by -log2(e); n_i,n_h by -2*log2(e), so the
// kernel computes sigmoid(x) = rcp(1+exp2(acc)) and tanh via exp2 directly.
// A k-map: k0-3 = x(z0,z1,z2,act), k4-19 = h0..15, k20-31 = 0
// A2 rows m: 0-2 = W_mu, 3-5 = W_lv; k20 = bias slot (B2[20][n] = 1.0)

__global__ __launch_bounds__(64) void prep_kernel(
    const float* __restrict__ W_ih, const float* __restrict__ W_hh,
    const float* __restrict__ b_ih, const float* __restrict__ b_hh,
    const float* __restrict__ W_mu, const float* __restrict__ b_mu,
    const float* __restrict__ W_lv, const float* __restrict__ b_lv,
    void* __restrict__ wsv)
{
    _Float16* wsB = (_Float16*)wsv;
    const int l = threadIdx.x;
    const int col = l & 15, kg = l >> 4;

    #pragma unroll
    for (int t = 0; t < 4; ++t) {
        const int gate = (t == 0) ? col : (t == 1) ? (16 + col) : (32 + col);
        const float scale = (t <= 1) ? -LOG2E : -2.0f * LOG2E;
        #pragma unroll
        for (int i = 0; i < 8; ++i) {
            const int k = kg * 8 + i;
            float v = 0.f;
            if (t <= 1) {
                if (k < 4)       v = W_ih[gate * 4 + k];
                else if (k < 20) v = W_hh[gate * 16 + (k - 4)];
            } else if (t == 2) {
                if (k < 4)       v = W_ih[gate * 4 + k];
            } else {
                if (k >= 4 && k < 20) v = W_hh[gate * 16 + (k - 4)];
            }
            wsB[t * 512 + l * 8 + i] = (_Float16)(v * scale);
        }
    }
    // tile 4: hp identity  B[k][n] = (k == n+4)   (unscaled)
    #pragma unroll
    for (int i = 0; i < 8; ++i) {
        const int k = kg * 8 + i;
        wsB[4 * 512 + l * 8 + i] = (_Float16)((k == col + 4) ? 1.f : 0.f);
    }
    // tile 5: A2  lane holds A2[m = col][k = kg*8+i]   (unscaled)
    #pragma unroll
    for (int i = 0; i < 8; ++i) {
        const int k = kg * 8 + i;
        const int m = col;
        float v = 0.f;
        if (m < 3) {
            if (k < 16)       v = W_mu[m * 16 + k];
            else if (k == 20) v = b_mu[m];
        } else if (m < 6) {
            if (k < 16)       v = W_lv[(m - 3) * 16 + k];
            else if (k == 20) v = b_lv[m - 3];
        }
        wsB[5 * 512 + l * 8 + i] = (_Float16)v;
    }
    if (l < 16) {
        float4* b4 = (float4*)((char*)wsv + 6144);
        b4[l] = make_float4(-LOG2E * (b_ih[l] + b_hh[l]),
                            -LOG2E * (b_ih[16 + l] + b_hh[16 + l]),
                            -2.0f * LOG2E * b_ih[32 + l],
                            -2.0f * LOG2E * b_hh[32 + l]);
    }
}

template<bool EXACT>
__global__ __launch_bounds__(TPB, 6) void rssm_kernel(
    const float* __restrict__ prev_z,   // [B,3]
    const float* __restrict__ action,   // [B,1]
    const float* __restrict__ prev_h,   // [B,16]
    const void*  __restrict__ wsv,
    float* __restrict__ out_mu,         // [B,3]
    float* __restrict__ out_lv,         // [B,3]
    float* __restrict__ out_h,          // [B,16]
    int B)
{
    __shared__ float lds[4][LDS_WAVE_F32];
    const int tid = threadIdx.x;
    const int wid = tid >> 6, lane = tid & 63;
    const int col = lane & 15, kg = lane >> 4;
    const int wbase = (blockIdx.x * 4 + wid) * 64;
    if (!EXACT && wbase >= B) return;

    float* W  = lds[wid];
    float* MU = W + LDS_ROW_F32;
    float* LV = MU + LDS_MU_F32;

    // ---- wave-invariant fragments ----
    const half8* Bp = (const half8*)wsv;
    const half8 bR  = Bp[lane];
    const half8 bZ  = Bp[64 + lane];
    const half8 bNi = Bp[128 + lane];
    const half8 bNh = Bp[192 + lane];
    const half8 bHp = Bp[256 + lane];
    const half8 a2  = Bp[320 + lane];
    const float4 bias = ((const float4*)((const char*)wsv + 6144))[col];

    // ---- stage this wave's 64 rows into LDS (coalesced, wave-private) ----
    {
        const float4* hg = (const float4*)prev_h;
        #pragma unroll
        for (int i = 0; i < 4; ++i) {
            const int fi = i * 64 + lane;               // 0..255
            const int r = fi >> 2, w = fi & 3;
            const int gi = EXACT ? (wbase * 4 + fi) : min(wbase * 4 + fi, B * 4 - 1);
            const float4 v = hg[gi];
            *(float4*)&W[r * ROW_DW + 4 + w * 4] = v;
        }
        const int zr = EXACT ? (wbase + lane) : min(wbase + lane, B - 1);
        const float z0 = prev_z[zr * 3 + 0];
        const float z1 = prev_z[zr * 3 + 1];
        const float z2 = prev_z[zr * 3 + 2];
        const float ac = action[zr];
        *(float4*)&W[lane * ROW_DW] = make_float4(z0, z1, z2, ac);
    }
    // no barrier: each wave reads only its own LDS slice (lgkmcnt ordering)

    #pragma unroll
    for (int t = 0; t < WPT; ++t) {
        // ---- A fragment (uniform LDS reads; k>=20 lanes hold zeros) ----
        const float* ap = &W[(t * 16 + col) * ROW_DW + kg * 8];
        const float4 z4 = make_float4(0.f, 0.f, 0.f, 0.f);
        const float4 p0 = (kg < 3) ? *(const float4*)ap : z4;
        const float4 p1 = (kg < 2) ? *(const float4*)(ap + 4) : z4;
        const half8 a = pack8(p0, p1);

        f32x4 accR  = {bias.x, bias.x, bias.x, bias.x};
        f32x4 accZ  = {bias.y, bias.y, bias.y, bias.y};
        f32x4 accNi = {bias.z, bias.z, bias.z, bias.z};
        f32x4 accNh = {bias.w, bias.w, bias.w, bias.w};
        f32x4 accHp = {0.f, 0.f, 0.f, 0.f};
        accR  = __builtin_amdgcn_mfma_f32_16x16x32_f16(a, bR,  accR,  0, 0, 0);
        accZ  = __builtin_amdgcn_mfma_f32_16x16x32_f16(a, bZ,  accZ,  0, 0, 0);
        accNi = __builtin_amdgcn_mfma_f32_16x16x32_f16(a, bNi, accNi, 0, 0, 0);
        accNh = __builtin_amdgcn_mfma_f32_16x16x32_f16(a, bNh, accNh, 0, 0, 0);
        accHp = __builtin_amdgcn_mfma_f32_16x16x32_f16(a, bHp, accHp, 0, 0, 0);

        // ---- gates (exp2-folded); write hn back into the LDS h-slot ----
        #pragma unroll
        for (int q = 0; q < 4; ++q) {
            const float r  = __builtin_amdgcn_rcpf(1.0f + __builtin_amdgcn_exp2f(accR[q]));
            const float z  = __builtin_amdgcn_rcpf(1.0f + __builtin_amdgcn_exp2f(accZ[q]));
            const float ta = fmaf(r, accNh[q], accNi[q]);            // -2*log2e * y
            const float n  = fmaf(2.0f,
                                  __builtin_amdgcn_rcpf(1.0f + __builtin_amdgcn_exp2f(ta)),
                                  -1.0f);                             // tanh(y)
            const float hv = fmaf(z, accHp[q] - n, n);                // (1-z)*n + z*h
            W[(t * 16 + kg * 4 + q) * ROW_DW + 4 + col] = hv;
        }

        // ---- head MFMA: B2[k][n=col] = hn[col][k] ----
        half8 b2;
        if (kg < 2) {
            const float* hr = &W[(t * 16 + col) * ROW_DW + 4 + kg * 8];
            b2 = pack8(*(const float4*)hr, *(const float4*)(hr + 4));
        } else {
            #pragma unroll
            for (int i = 0; i < 8; ++i) b2[i] = (_Float16)0.f;
            if (kg == 2) b2[4] = (_Float16)1.0f;         // k=20 bias slot
        }
        f32x4 acc2 = {0.f, 0.f, 0.f, 0.f};
        acc2 = __builtin_amdgcn_mfma_f32_16x16x32_f16(a2, b2, acc2, 0, 0, 0);

        // mu/lv into LDS (clamped), packed [row][3] per stream
        const int mr = (t * 16 + col) * 3;
        if (kg == 0) {
            MU[mr + 0] = acc2[0];
            MU[mr + 1] = acc2[1];
            MU[mr + 2] = acc2[2];
            LV[mr + 0] = fminf(fmaxf(acc2[3], -5.0f), 5.0f);
        } else if (kg == 1) {
            LV[mr + 1] = fminf(fmaxf(acc2[0], -5.0f), 5.0f);
            LV[mr + 2] = fminf(fmaxf(acc2[1], -5.0f), 5.0f);
        }

        // ---- cooperative out_h store for this tile (1 KB contiguous) ----
        {
            const int r = lane >> 2, w = lane & 3;
            const float4 hv4 = *(const float4*)&W[(t * 16 + r) * ROW_DW + 4 + w * 4];
            const int orow = wbase + t * 16 + r;
            if (EXACT || orow < B)
                *(float4*)&out_h[(size_t)orow * 16 + w * 4] = hv4;
        }
    }

    // ---- cooperative mu / lv stores (768 B contiguous each) ----
    if (lane < 48) {
        const int gi = wbase * 3 + lane * 4;
        if (EXACT || gi + 3 < B * 3) {
            *(float4*)&out_mu[gi] = *(const float4*)&MU[lane * 4];
            *(float4*)&out_lv[gi] = *(const float4*)&LV[lane * 4];
        }
    }
}

extern "C" void kernel_launch(void* const* d_in, const int* in_sizes, int n_in,
                              void* d_out, int out_size, void* d_ws, size_t ws_size,
                              hipStream_t stream) {
    const float* prev_z = (const float*)d_in[0];
    const float* action = (const float*)d_in[1];
    const float* prev_h = (const float*)d_in[2];
    const float* W_ih   = (const float*)d_in[3];
    const float* W_hh   = (const float*)d_in[4];
    const float* b_ih   = (const float*)d_in[5];
    const float* b_hh   = (const float*)d_in[6];
    const float* W_mu   = (const float*)d_in[7];
    const float* b_mu   = (const float*)d_in[8];
    const float* W_lv   = (const float*)d_in[9];
    const float* b_lv   = (const float*)d_in[10];

    const int B = in_sizes[0] / 3;
    float* out    = (float*)d_out;
    float* out_mu = out;
    float* out_lv = out + (size_t)3 * B;
    float* out_h  = out + (size_t)6 * B;

    prep_kernel<<<1, 64, 0, stream>>>(W_ih, W_hh, b_ih, b_hh,
                                      W_mu, b_mu, W_lv, b_lv, d_ws);

    const int rows_per_block = 256;
    const int blocks = (B + rows_per_block - 1) / rows_per_block;
    if ((B % rows_per_block) == 0)
        rssm_kernel<true><<<blocks, TPB, 0, stream>>>(prev_z, action, prev_h, d_ws,
                                                      out_mu, out_lv, out_h, B);
    else
        rssm_kernel<false><<<blocks, TPB, 0, stream>>>(prev_z, action, prev_h, d_ws,
                                                       out_mu, out_lv, out_h, B);
}